// Round 7
// baseline (198.959 us; speedup 1.0000x reference)
//
#include <hip/hip_runtime.h>
#include <hip/hip_bf16.h>
#include <math.h>

#define CDIM 192
#define NHEADS 6
#define WIN 7
#define KWIN 49
#define BATCH 4
#define PIX 3136      // 56*56
#define NPIX 12544    // BATCH*PIX
#define NIMG 24       // BATCH*NHEADS
#define EPSV 1e-5f

typedef __bf16 bf16x8 __attribute__((ext_vector_type(8)));
typedef float f32x16 __attribute__((ext_vector_type(16)));
typedef unsigned int uint4v __attribute__((ext_vector_type(4)));
typedef unsigned short u16;

// ---------------- BN stats ---------------------------------------------------
__global__ __launch_bounds__(256) void bn_stats_k(const float* __restrict__ x,
                                                  float* __restrict__ stats) {
  int c = blockIdx.x;
  float s = 0.f, q = 0.f;
  for (int n = threadIdx.x; n < BATCH * PIX; n += 256) {
    int b = n / PIX, p = n - b * PIX;
    float v = x[((size_t)b * CDIM + c) * PIX + p];
    s += v; q += v * v;
  }
  __shared__ float rs[256], rq[256];
  rs[threadIdx.x] = s; rq[threadIdx.x] = q;
  __syncthreads();
  for (int st = 128; st > 0; st >>= 1) {
    if (threadIdx.x < st) { rs[threadIdx.x] += rs[threadIdx.x + st]; rq[threadIdx.x] += rq[threadIdx.x + st]; }
    __syncthreads();
  }
  if (threadIdx.x == 0) {
    float mean = rs[0] / (float)(BATCH * PIX);
    float var = rq[0] / (float)(BATCH * PIX) - mean * mean;
    stats[c] = mean;
    stats[CDIM + c] = rsqrtf(var + EPSV);
  }
}

// ---------------- fold BN + q-scale into qkv weights ------------------------
__global__ __launch_bounds__(192) void fold_k(const float* __restrict__ qkv_w,
                                              const float* __restrict__ qkv_b,
                                              const float* __restrict__ gamma,
                                              const float* __restrict__ beta,
                                              const float* __restrict__ stats,
                                              float* __restrict__ w_eff,
                                              float* __restrict__ b_eff) {
  int o = blockIdx.x, c = threadIdx.x;
  float alpha = gamma[c] * stats[CDIM + c];
  float shift = beta[c] - stats[c] * alpha;
  float w = qkv_w[o * CDIM + c];
  float scale = (o < CDIM) ? 0.17677669529663687f : 1.f;
  w_eff[o * CDIM + c] = w * alpha * scale;
  __shared__ float r[CDIM];
  r[c] = w * shift;
  __syncthreads();
  if (c == 0) {
    float s = 0.f;
    for (int i = 0; i < CDIM; i++) s += r[i];
    b_eff[o] = (qkv_b[o] + s) * scale;
  }
}

// ---------------- pack dm_w (attn conv weights) frag-major ------------------
__global__ __launch_bounds__(256) void wprep_k(const float* __restrict__ dm_w,
                                               __hip_bfloat16* __restrict__ wTb2) {
  int idx = blockIdx.x * 256 + threadIdx.x;
  if (idx >= 200704) return;
  int e = idx & 7;
  int tmp = idx >> 3;
  int lane = tmp & 63; tmp >>= 6;
  int ch = tmp & 3; tmp >>= 2;
  int tap = tmp % 49, Mt = tmp / 49;
  int ko = Mt * 32 + (lane & 31);
  int ci = ch * 16 + (lane >> 5) * 8 + e;
  float v = (ko < KWIN) ? dm_w[(size_t)ko * 3136 + ci * 49 + tap] : 0.f;
  wTb2[idx] = __float2bfloat16(v);
}

// ---------------- generic GEMM weight pack: W[Cout][Cin] -> frag-major ------
__global__ __launch_bounds__(256) void pack_k(const float* __restrict__ W,
                                              u16* __restrict__ out,
                                              int Cin, int total8) {
  int t = blockIdx.x * 256 + threadIdx.x;
  if (t >= total8) return;
  int lane = t & 63, rest = t >> 6;
  int nK = Cin >> 4;
  int kk = rest % nK, mtg = rest / nK;
  int o = mtg * 32 + (lane & 31), c = kk * 16 + (lane >> 5) * 8;
  const float* src = W + (size_t)o * Cin + c;
  __hip_bfloat16 tmp[8];
#pragma unroll
  for (int e = 0; e < 8; e++) tmp[e] = __float2bfloat16(src[e]);
  *(uint4v*)(out + (size_t)t * 8) = *(uint4v*)tmp;
}

// ---------------- x [b][c][p] fp32 -> xT [b*p][192] bf16 --------------------
__global__ __launch_bounds__(256) void xT_k(const float* __restrict__ x,
                                            u16* __restrict__ xT) {
  __shared__ float Ls[64][33];
  int bb = blockIdx.x / 49;
  int p0 = (blockIdx.x % 49) * 64;
  int c0 = blockIdx.y * 32;
  int tid = threadIdx.x;
  int j = tid & 63;
#pragma unroll
  for (int it = 0; it < 8; it++) {
    int c = it * 4 + (tid >> 6);
    Ls[j][c] = x[((size_t)bb * CDIM + c0 + c) * PIX + p0 + j];
  }
  __syncthreads();
  int jr = tid >> 2, t = tid & 3;
  __hip_bfloat16 tmp[8];
#pragma unroll
  for (int u = 0; u < 8; u++) tmp[u] = __float2bfloat16(Ls[jr][t * 8 + u]);
  *(uint4v*)(xT + (size_t)(bb * PIX + p0 + jr) * CDIM + c0 + t * 8) = *(uint4v*)tmp;
}

// ---------------- MFMA GEMM: Y[o][gp] = sum_c W[o][c] * Bm[gp][c] -----------
#define MG_QKV 0
#define MG_PROJ 1
#define MG_GELU 2
#define MG_C2 3
#define MGS 2056

template <int EPI>
__global__ __launch_bounds__(256) void mgemm_k(
    const u16* __restrict__ Bm, const u16* __restrict__ Apk,
    const float* __restrict__ bias,
    float* __restrict__ outF, u16* __restrict__ outT,
    const float* __restrict__ extra, int Cin) {
  __shared__ __align__(16) u16 Bs[8 * MGS];  // 32.9 KB
  int tid = threadIdx.x;
  int lane = tid & 63, wid = tid >> 6;
  int hi = lane >> 5, ln31 = lane & 31;
  int p0 = blockIdx.x * 256;
  int o0 = blockIdx.y * 64;
  int nK = Cin >> 4;
  f32x16 acc[2][2];
#pragma unroll
  for (int mt = 0; mt < 2; mt++)
#pragma unroll
    for (int nt = 0; nt < 2; nt++)
#pragma unroll
      for (int i = 0; i < 16; i++) acc[mt][nt][i] = 0.f;

  for (int cc = 0; cc < Cin; cc += 64) {
#pragma unroll
    for (int i = 0; i < 8; i++) {
      int idx = i * 256 + tid;
      int g = idx & 7, p = idx >> 3;
      uint4v v = *(const uint4v*)(Bm + (size_t)(p0 + p) * Cin + cc + g * 8);
      *(uint4v*)&Bs[g * MGS + p * 8] = v;
    }
    __syncthreads();
    const u16* Ab = Apk + ((size_t)(o0 >> 5) * nK + (cc >> 4)) * 512 + lane * 8;
    int pA = wid * 64 + ln31;
    int pB = pA + 32;
#pragma unroll
    for (int ks = 0; ks < 4; ks++) {
      int g = ks * 2 + hi;
      bf16x8 b0 = *(const bf16x8*)&Bs[g * MGS + pA * 8];
      bf16x8 b1 = *(const bf16x8*)&Bs[g * MGS + pB * 8];
      bf16x8 a0 = *(const bf16x8*)(Ab + ks * 512);
      bf16x8 a1 = *(const bf16x8*)(Ab + (nK + ks) * 512);
      acc[0][0] = __builtin_amdgcn_mfma_f32_32x32x16_bf16(a0, b0, acc[0][0], 0, 0, 0);
      acc[0][1] = __builtin_amdgcn_mfma_f32_32x32x16_bf16(a0, b1, acc[0][1], 0, 0, 0);
      acc[1][0] = __builtin_amdgcn_mfma_f32_32x32x16_bf16(a1, b0, acc[1][0], 0, 0, 0);
      acc[1][1] = __builtin_amdgcn_mfma_f32_32x32x16_bf16(a1, b1, acc[1][1], 0, 0, 0);
    }
    __syncthreads();
  }

  // ---- epilogue ----
  if (EPI == MG_C2 || (EPI == MG_QKV && o0 >= 384)) {
#pragma unroll
    for (int mt = 0; mt < 2; mt++)
#pragma unroll
      for (int r = 0; r < 16; r++) {
        int o = o0 + mt * 32 + (r & 3) + 8 * (r >> 2) + 4 * hi;
        float bv = bias[o];
#pragma unroll
        for (int nt = 0; nt < 2; nt++) {
          unsigned gp = p0 + wid * 64 + nt * 32 + ln31;
          unsigned bb = gp / PIX, pp = gp - bb * PIX;
          if (EPI == MG_C2) {
            size_t oi = ((size_t)bb * CDIM + o) * PIX + pp;
            outF[oi] = acc[mt][nt][r] + bv + extra[oi];
          } else {  // v
            int ch = o - 384;
            outF[((size_t)(bb * NHEADS + (ch >> 5)) * 32 + (ch & 31)) * PIX + pp] =
                acc[mt][nt][r] + bv;
          }
        }
      }
  } else {
    // bf16-transposed output via wave-local LDS transpose (Bs reused as scratch)
#pragma unroll
    for (int mt = 0; mt < 2; mt++)
#pragma unroll
      for (int r = 0; r < 16; r++) {
        int o_loc = mt * 32 + (r & 3) + 8 * (r >> 2) + 4 * hi;
        int o = o0 + o_loc;
        float bv = bias[o];
#pragma unroll
        for (int nt = 0; nt < 2; nt++) {
          int p_loc = wid * 64 + nt * 32 + ln31;
          float val = acc[mt][nt][r] + bv;
          if (EPI == MG_PROJ) {
            unsigned gp = p0 + p_loc;
            unsigned bb = gp / PIX, pp = gp - bb * PIX;
            size_t oi = ((size_t)bb * CDIM + o) * PIX + pp;
            val += extra[oi];
            outF[oi] = val;
          }
          if (EPI == MG_GELU)
            val = 0.5f * val * (1.f + erff(val * 0.70710678118654752f));
          *(__hip_bfloat16*)&Bs[p_loc * 64 + (((o_loc >> 3) ^ (p_loc & 7)) << 3) + (o_loc & 7)] =
              __float2bfloat16(val);
        }
      }
    int prow = wid * 64 + lane;
    int psw = prow & 7;
    uint4v r8[8];
#pragma unroll
    for (int g = 0; g < 8; g++)
      r8[g] = *(const uint4v*)&Bs[prow * 64 + ((g ^ psw) << 3)];
    unsigned gp = p0 + prow;
    if (EPI == MG_QKV) {
      unsigned bb = gp / PIX, pp = gp - bb * PIX;
      int s = (o0 >= 192) ? 1 : 0;
      int h0 = (o0 - s * 192) >> 5;
      u16* d0 = outT + ((size_t)(bb * NHEADS + h0) * PIX + pp) * 64 + s * 32;
      u16* d1 = outT + ((size_t)(bb * NHEADS + h0 + 1) * PIX + pp) * 64 + s * 32;
      *(uint4v*)(d0) = r8[0]; *(uint4v*)(d0 + 8) = r8[1];
      *(uint4v*)(d0 + 16) = r8[2]; *(uint4v*)(d0 + 24) = r8[3];
      *(uint4v*)(d1) = r8[4]; *(uint4v*)(d1 + 8) = r8[5];
      *(uint4v*)(d1 + 16) = r8[6]; *(uint4v*)(d1 + 24) = r8[7];
    } else if (EPI == MG_PROJ) {
      u16* d = outT + (size_t)gp * CDIM + o0;
#pragma unroll
      for (int g = 0; g < 8; g++) *(uint4v*)(d + g * 8) = r8[g];
    } else {  // GELU -> hT [gp][768]
      u16* d = outT + (size_t)gp * 768 + o0;
#pragma unroll
      for (int g = 0; g < 8; g++) *(uint4v*)(d + g * 8) = r8[g];
    }
  }
}

// ---------------- 7x7 attn conv: 8x4 tile, 2-img, 4-way Ks-split ------------
// Block = (tile 8x4 px, img-pair). 4 waves, wave = ks in 0..3. acc[im][Mt]
// (64 VGPR): per tap 2 A-loads + 2 B ds_reads + 4 MFMAs. Grid 1176, LDS 35.3KB
// -> 4 blocks/CU, 16 waves/CU (fixes round5/6 latency-bound 2.3 blocks/CU).
// Ks-partials combined by 2-stage butterfly LDS reduction (wid^1: img swap,
// wid^2: Mt swap), rbuf aliases dead patch. Compile-time acc indices only.
#define AGS2 1128             // granule stride u16 (141*8)
#define AIMS2 (8 * AGS2)      // 9024 u16 per image
__global__ __launch_bounds__(256, 4) void attn_mfma_k(
    const u16* __restrict__ qkT, const u16* __restrict__ wTb2,
    const float* __restrict__ dm_b, const float* __restrict__ rel_bias,
    float* __restrict__ attnL) {
  __shared__ __align__(16) u16 patch[2 * AIMS2];  // 36096 B
  int tile = blockIdx.x % 98;
  int pair = blockIdx.x / 98;
  int y0 = (tile / 7) * 4, x0 = (tile % 7) * 8;
  int tid = threadIdx.x;

  // stage 2 patches (10 rows x 14 cols x 64ch); g-minor lanes => coalesced
  for (int idx = tid; idx < 2240; idx += 256) {
    int g = idx & 7;
    int t2 = idx >> 3;
    int im = t2 / 140, lp = t2 - im * 140;
    int row = lp / 14, col = lp - row * 14;
    int gy = y0 - 3 + row, gx = x0 - 3 + col;
    uint4v val = {0u, 0u, 0u, 0u};
    if ((unsigned)gy < 56u && (unsigned)gx < 56u)
      val = *(const uint4v*)(qkT + ((size_t)(pair * 2 + im) * PIX + gy * 56 + gx) * 64 + g * 8);
    *(uint4v*)&patch[im * AIMS2 + g * AGS2 + lp * 8] = val;
  }
  __syncthreads();

  int lane = tid & 63, wid = tid >> 6;   // wid = ks
  int n = lane & 31, hi = lane >> 5;
  int py = n >> 3, px = n & 7;           // 4 rows x 8 cols
  f32x16 acc[2][2];                      // [im][Mt]
#pragma unroll
  for (int im = 0; im < 2; im++)
#pragma unroll
    for (int mt = 0; mt < 2; mt++)
#pragma unroll
      for (int i = 0; i < 16; i++) acc[im][mt][i] = 0.f;

  const u16* Ab = wTb2 + wid * 512 + lane * 8;
  int gbase = (wid * 2 + hi) * AGS2;
#pragma unroll
  for (int kh = 0; kh < 7; kh++) {
#pragma unroll
    for (int kw = 0; kw < 7; kw++) {
      int tap = kh * 7 + kw;
      int goff = gbase + ((py + kh) * 14 + px + kw) * 8;
      const u16* Af = Ab + (size_t)tap * 2048;
      bf16x8 a0 = __builtin_bit_cast(bf16x8, *(const uint4v*)(Af));
      bf16x8 a1 = __builtin_bit_cast(bf16x8, *(const uint4v*)(Af + 100352));
      bf16x8 b0 = __builtin_bit_cast(bf16x8, *(const uint4v*)&patch[goff]);
      bf16x8 b1 = __builtin_bit_cast(bf16x8, *(const uint4v*)&patch[AIMS2 + goff]);
      acc[0][0] = __builtin_amdgcn_mfma_f32_32x32x16_bf16(a0, b0, acc[0][0], 0, 0, 0);
      acc[0][1] = __builtin_amdgcn_mfma_f32_32x32x16_bf16(a1, b0, acc[0][1], 0, 0, 0);
      acc[1][0] = __builtin_amdgcn_mfma_f32_32x32x16_bf16(a0, b1, acc[1][0], 0, 0, 0);
      acc[1][1] = __builtin_amdgcn_mfma_f32_32x32x16_bf16(a1, b1, acc[1][1], 0, 0, 0);
    }
  }

  // ---- stage 1: wid^1 exchanges the non-owned image (im_own = wid&1) -------
  float* rbuf = (float*)patch;  // 4 waves x 8 x 64 lanes x 16B = 32 KB
  __syncthreads();
#pragma unroll
  for (int mt = 0; mt < 2; mt++)
#pragma unroll
    for (int q = 0; q < 4; q++) {
      float4 v4;
      if ((wid & 1) == 0)
        v4 = make_float4(acc[1][mt][q * 4], acc[1][mt][q * 4 + 1],
                         acc[1][mt][q * 4 + 2], acc[1][mt][q * 4 + 3]);
      else
        v4 = make_float4(acc[0][mt][q * 4], acc[0][mt][q * 4 + 1],
                         acc[0][mt][q * 4 + 2], acc[0][mt][q * 4 + 3]);
      *(float4*)&rbuf[(((wid * 8) + mt * 4 + q) * 64 + lane) * 4] = v4;
    }
  __syncthreads();
  int p1 = wid ^ 1;
#pragma unroll
  for (int mt = 0; mt < 2; mt++)
#pragma unroll
    for (int q = 0; q < 4; q++) {
      float4 v4 = *(const float4*)&rbuf[(((p1 * 8) + mt * 4 + q) * 64 + lane) * 4];
      if ((wid & 1) == 0) {
        acc[0][mt][q * 4] += v4.x; acc[0][mt][q * 4 + 1] += v4.y;
        acc[0][mt][q * 4 + 2] += v4.z; acc[0][mt][q * 4 + 3] += v4.w;
      } else {
        acc[1][mt][q * 4] += v4.x; acc[1][mt][q * 4 + 1] += v4.y;
        acc[1][mt][q * 4 + 2] += v4.z; acc[1][mt][q * 4 + 3] += v4.w;
      }
    }

  // ---- stage 2: wid^2 exchanges the non-owned Mt (mt_own = wid>>1) ---------
  __syncthreads();
#pragma unroll
  for (int q = 0; q < 4; q++) {
    float4 v4;
    if ((wid & 1) == 0) {
      if ((wid >> 1) == 0)
        v4 = make_float4(acc[0][1][q * 4], acc[0][1][q * 4 + 1],
                         acc[0][1][q * 4 + 2], acc[0][1][q * 4 + 3]);
      else
        v4 = make_float4(acc[0][0][q * 4], acc[0][0][q * 4 + 1],
                         acc[0][0][q * 4 + 2], acc[0][0][q * 4 + 3]);
    } else {
      if ((wid >> 1) == 0)
        v4 = make_float4(acc[1][1][q * 4], acc[1][1][q * 4 + 1],
                         acc[1][1][q * 4 + 2], acc[1][1][q * 4 + 3]);
      else
        v4 = make_float4(acc[1][0][q * 4], acc[1][0][q * 4 + 1],
                         acc[1][0][q * 4 + 2], acc[1][0][q * 4 + 3]);
    }
    *(float4*)&rbuf[(((wid * 8) + q) * 64 + lane) * 4] = v4;
  }
  __syncthreads();
  int p2 = wid ^ 2;
  float fin[16];
#pragma unroll
  for (int q = 0; q < 4; q++) {
    float4 v4 = *(const float4*)&rbuf[(((p2 * 8) + q) * 64 + lane) * 4];
    float o0, o1, o2, o3;
    if ((wid & 1) == 0) {
      if ((wid >> 1) == 0) {
        o0 = acc[0][0][q * 4]; o1 = acc[0][0][q * 4 + 1];
        o2 = acc[0][0][q * 4 + 2]; o3 = acc[0][0][q * 4 + 3];
      } else {
        o0 = acc[0][1][q * 4]; o1 = acc[0][1][q * 4 + 1];
        o2 = acc[0][1][q * 4 + 2]; o3 = acc[0][1][q * 4 + 3];
      }
    } else {
      if ((wid >> 1) == 0) {
        o0 = acc[1][0][q * 4]; o1 = acc[1][0][q * 4 + 1];
        o2 = acc[1][0][q * 4 + 2]; o3 = acc[1][0][q * 4 + 3];
      } else {
        o0 = acc[1][1][q * 4]; o1 = acc[1][1][q * 4 + 1];
        o2 = acc[1][1][q * 4 + 2]; o3 = acc[1][1][q * 4 + 3];
      }
    }
    fin[q * 4] = o0 + v4.x; fin[q * 4 + 1] = o1 + v4.y;
    fin[q * 4 + 2] = o2 + v4.z; fin[q * 4 + 3] = o3 + v4.w;
  }

  // ---- epilogue: wave owns (img = pair*2 + (wid&1), Mt = wid>>1) -----------
  int img = pair * 2 + (wid & 1);
  int mt = wid >> 1;
  int head = img % NHEADS;
  int pout = (y0 + py) * 56 + x0 + px;
  float* outb = attnL + (size_t)img * KWIN * PIX + pout;
#pragma unroll
  for (int r = 0; r < 16; r++) {
    int ko = mt * 32 + (r & 3) + 8 * (r >> 2) + 4 * hi;
    if (ko < KWIN)
      outb[(size_t)ko * PIX] = fin[r] + dm_b[ko] + rel_bias[ko * NHEADS + head];
  }
}

// ---------------- softmax(49) + v-patch aggregation -> attnoT bf16 ----------
__global__ __launch_bounds__(256) void softagg_k(const float* __restrict__ attnL,
                                                 const float* __restrict__ v,
                                                 u16* __restrict__ attnoT) {
  __shared__ float vp[32][196];
  int img = blockIdx.x / 49, tile = blockIdx.x % 49;
  int y0 = (tile / 7) * 8, x0 = (tile % 7) * 8;
  int tid = threadIdx.x;
  const float* vi = v + (size_t)img * 32 * PIX;
  for (int idx = tid; idx < 32 * 196; idx += 256) {
    int ch = idx / 196, rr = idx - ch * 196;
    int r = rr / 14, cc2 = rr - r * 14;
    int gy = y0 - 3 + r, gx = x0 - 3 + cc2;
    vp[ch][rr] = ((unsigned)gy < 56u && (unsigned)gx < 56u)
                     ? vi[(size_t)ch * PIX + gy * 56 + gx] : 0.f;
  }
  __syncthreads();
  int px = tid & 7, py = (tid >> 3) & 7, cq = tid >> 6;
  int p = (y0 + py) * 56 + x0 + px;
  const float* al = attnL + (size_t)img * KWIN * PIX + p;
  float a[49];
  float m = -1e30f;
#pragma unroll
  for (int k = 0; k < KWIN; k++) { a[k] = al[(size_t)k * PIX]; m = fmaxf(m, a[k]); }
  float s = 0.f;
#pragma unroll
  for (int k = 0; k < KWIN; k++) { a[k] = __expf(a[k] - m); s += a[k]; }
  float inv = 1.f / s;
  int b = img / NHEADS, head = img % NHEADS;
  __hip_bfloat16 ob[8];
#pragma unroll
  for (int c8 = 0; c8 < 8; c8++) {
    int c = cq * 8 + c8;
    float accv = 0.f;
#pragma unroll
    for (int kh = 0; kh < 7; kh++)
#pragma unroll
      for (int kw = 0; kw < 7; kw++)
        accv += a[kh * 7 + kw] * vp[c][(py + kh) * 14 + px + kw];
    ob[c8] = __float2bfloat16(accv * inv);
  }
  *(uint4v*)(attnoT + ((size_t)b * PIX + p) * CDIM + head * 32 + cq * 8) = *(uint4v*)ob;
}

// ---------------- launch ----------------------------------------------------
extern "C" void kernel_launch(void* const* d_in, const int* in_sizes, int n_in,
                              void* d_out, int out_size, void* d_ws, size_t ws_size,
                              hipStream_t stream) {
  const float* x        = (const float*)d_in[0];
  const float* bn_gamma = (const float*)d_in[1];
  const float* bn_beta  = (const float*)d_in[2];
  const float* qkv_w    = (const float*)d_in[3];
  const float* qkv_b    = (const float*)d_in[4];
  const float* dm_w     = (const float*)d_in[5];
  const float* dm_b     = (const float*)d_in[6];
  const float* rel_bias = (const float*)d_in[7];
  const float* proj_w   = (const float*)d_in[8];
  const float* proj_b   = (const float*)d_in[9];
  const float* c1_w     = (const float*)d_in[10];
  const float* c1_b     = (const float*)d_in[11];
  const float* c2_w     = (const float*)d_in[12];
  const float* c2_b     = (const float*)d_in[13];
  float* out = (float*)d_out;
  float* ws  = (float*)d_ws;

  float* stats   = ws;
  float* w_eff   = stats + 384;
  float* b_eff   = w_eff + 110592;
  u16*   pk_qkv  = (u16*)(b_eff + 576);      // 110592 u16
  u16*   pk_proj = pk_qkv + 110592;          // 36864
  u16*   pk_c1   = pk_proj + 36864;          // 147456
  u16*   pk_c2   = pk_c1 + 147456;           // 147456
  u16*   wTb2    = pk_c2 + 147456;           // 200704
  u16*   xT      = wTb2 + 200704;            // 2408448 u16
  u16*   qkT     = xT + 2408448;             // 4816896 u16
  float* vbuf    = (float*)(qkT + 4816896);  // 2408448 f
  float* attnL   = vbuf + 2408448;           // 3687936 f
  u16*   attnoT  = (u16*)(attnL + 3687936);  // 2408448 u16
  float* x1      = (float*)(attnoT + 2408448);  // 2408448 f
  u16*   x1T     = (u16*)(x1 + 2408448);     // 2408448 u16
  u16*   hT      = xT;  // alias: 9633792 u16 over dead xT+qkT+vbuf

  bn_stats_k<<<CDIM, 256, 0, stream>>>(x, stats);
  fold_k<<<576, 192, 0, stream>>>(qkv_w, qkv_b, bn_gamma, bn_beta, stats, w_eff, b_eff);
  wprep_k<<<784, 256, 0, stream>>>(dm_w, (__hip_bfloat16*)wTb2);
  pack_k<<<54, 256, 0, stream>>>(w_eff, pk_qkv, 192, 13824);
  pack_k<<<18, 256, 0, stream>>>(proj_w, pk_proj, 192, 4608);
  pack_k<<<72, 256, 0, stream>>>(c1_w, pk_c1, 192, 18432);
  pack_k<<<72, 256, 0, stream>>>(c2_w, pk_c2, 768, 18432);
  xT_k<<<dim3(BATCH * 49, 6), 256, 0, stream>>>(x, xT);

  mgemm_k<MG_QKV><<<dim3(49, 9), 256, 0, stream>>>(
      xT, pk_qkv, b_eff, vbuf, qkT, nullptr, 192);
  attn_mfma_k<<<1176, 256, 0, stream>>>(qkT, wTb2, dm_b, rel_bias, attnL);
  softagg_k<<<NIMG * 49, 256, 0, stream>>>(attnL, vbuf, attnoT);
  mgemm_k<MG_PROJ><<<dim3(49, 3), 256, 0, stream>>>(
      attnoT, pk_proj, proj_b, x1, x1T, x, 192);
  mgemm_k<MG_GELU><<<dim3(49, 12), 256, 0, stream>>>(
      x1T, pk_c1, c1_b, nullptr, hT, nullptr, 192);
  mgemm_k<MG_C2><<<dim3(49, 3), 256, 0, stream>>>(
      hT, pk_c2, c2_b, out, nullptr, x1, 768);
}

// Round 8
// 160.682 us; speedup vs baseline: 1.2382x; 1.2382x over previous
//
#include <hip/hip_runtime.h>
#include <hip/hip_bf16.h>
#include <math.h>

#define CDIM 192
#define NHEADS 6
#define WIN 7
#define KWIN 49
#define BATCH 4
#define PIX 3136      // 56*56
#define NPIX 12544    // BATCH*PIX
#define NIMG 24       // BATCH*NHEADS
#define EPSV 1e-5f

typedef __bf16 bf16x8 __attribute__((ext_vector_type(8)));
typedef float f32x16 __attribute__((ext_vector_type(16)));
typedef unsigned int uint4v __attribute__((ext_vector_type(4)));
typedef unsigned short u16;

// ---------------- BN stats ---------------------------------------------------
__global__ __launch_bounds__(256) void bn_stats_k(const float* __restrict__ x,
                                                  float* __restrict__ stats) {
  int c = blockIdx.x;
  float s = 0.f, q = 0.f;
  for (int n = threadIdx.x; n < BATCH * PIX; n += 256) {
    int b = n / PIX, p = n - b * PIX;
    float v = x[((size_t)b * CDIM + c) * PIX + p];
    s += v; q += v * v;
  }
  __shared__ float rs[256], rq[256];
  rs[threadIdx.x] = s; rq[threadIdx.x] = q;
  __syncthreads();
  for (int st = 128; st > 0; st >>= 1) {
    if (threadIdx.x < st) { rs[threadIdx.x] += rs[threadIdx.x + st]; rq[threadIdx.x] += rq[threadIdx.x + st]; }
    __syncthreads();
  }
  if (threadIdx.x == 0) {
    float mean = rs[0] / (float)(BATCH * PIX);
    float var = rq[0] / (float)(BATCH * PIX) - mean * mean;
    stats[c] = mean;
    stats[CDIM + c] = rsqrtf(var + EPSV);
  }
}

// ------- fold BN + q-scale into qkv weights, writing PACKED frags directly --
__global__ __launch_bounds__(192) void fold_pack_k(
    const float* __restrict__ qkv_w, const float* __restrict__ qkv_b,
    const float* __restrict__ gamma, const float* __restrict__ beta,
    const float* __restrict__ stats, u16* __restrict__ pk_qkv,
    float* __restrict__ b_eff) {
  int o = blockIdx.x, c = threadIdx.x;
  float alpha = gamma[c] * stats[CDIM + c];
  float shift = beta[c] - stats[c] * alpha;
  float w = qkv_w[o * CDIM + c];
  float scale = (o < CDIM) ? 0.17677669529663687f : 1.f;
  // packed fragment position (nK = 12 for Cin=192)
  int t8 = ((((o >> 5) * 12 + (c >> 4)) * 64 + (((c >> 3) & 1) * 32 + (o & 31))) << 3) + (c & 7);
  ((__hip_bfloat16*)pk_qkv)[t8] = __float2bfloat16(w * alpha * scale);
  __shared__ float r[CDIM];
  r[c] = w * shift;
  __syncthreads();
  if (c == 0) {
    float s = 0.f;
    for (int i = 0; i < CDIM; i++) s += r[i];
    b_eff[o] = (qkv_b[o] + s) * scale;
  }
}

// ---------------- generic pack helper: W[Cout][Cin] -> frag-major -----------
__device__ inline void pack_one(const float* __restrict__ W, u16* __restrict__ out,
                                int Cin, int t) {
  int lane = t & 63, rest = t >> 6;
  int nK = Cin >> 4;
  int kk = rest % nK, mtg = rest / nK;
  int o = mtg * 32 + (lane & 31), c = kk * 16 + (lane >> 5) * 8;
  const float* src = W + (size_t)o * Cin + c;
  __hip_bfloat16 tmp[8];
#pragma unroll
  for (int e = 0; e < 8; e++) tmp[e] = __float2bfloat16(src[e]);
  *(uint4v*)(out + (size_t)t * 8) = *(uint4v*)tmp;
}

// --------- merged prep: dm_w frag pack (784 blk) + proj/c1/c2 packs ---------
__global__ __launch_bounds__(256) void prep2_k(
    const float* __restrict__ dm_w, u16* __restrict__ wTb2,
    const float* __restrict__ proj_w, u16* __restrict__ pk_proj,
    const float* __restrict__ c1_w, u16* __restrict__ pk_c1,
    const float* __restrict__ c2_w, u16* __restrict__ pk_c2) {
  int bid = blockIdx.x, tid = threadIdx.x;
  if (bid < 784) {
    int idx = bid * 256 + tid;   // < 200704 exactly
    int e = idx & 7;
    int tmp = idx >> 3;
    int lane = tmp & 63; tmp >>= 6;
    int ch = tmp & 3; tmp >>= 2;
    int tap = tmp % 49, Mt = tmp / 49;
    int ko = Mt * 32 + (lane & 31);
    int ci = ch * 16 + (lane >> 5) * 8 + e;
    float v = (ko < KWIN) ? dm_w[(size_t)ko * 3136 + ci * 49 + tap] : 0.f;
    ((__hip_bfloat16*)wTb2)[idx] = __float2bfloat16(v);
  } else if (bid < 802) {
    int t = (bid - 784) * 256 + tid;
    if (t < 4608) pack_one(proj_w, pk_proj, 192, t);
  } else if (bid < 874) {
    int t = (bid - 802) * 256 + tid;
    if (t < 18432) pack_one(c1_w, pk_c1, 192, t);
  } else {
    int t = (bid - 874) * 256 + tid;
    if (t < 18432) pack_one(c2_w, pk_c2, 768, t);
  }
}

// ---------------- x [b][c][p] fp32 -> xT [b*p][192] bf16 --------------------
__global__ __launch_bounds__(256) void xT_k(const float* __restrict__ x,
                                            u16* __restrict__ xT) {
  __shared__ float Ls[64][33];
  int bb = blockIdx.x / 49;
  int p0 = (blockIdx.x % 49) * 64;
  int c0 = blockIdx.y * 32;
  int tid = threadIdx.x;
  int j = tid & 63;
#pragma unroll
  for (int it = 0; it < 8; it++) {
    int c = it * 4 + (tid >> 6);
    Ls[j][c] = x[((size_t)bb * CDIM + c0 + c) * PIX + p0 + j];
  }
  __syncthreads();
  int jr = tid >> 2, t = tid & 3;
  __hip_bfloat16 tmp[8];
#pragma unroll
  for (int u = 0; u < 8; u++) tmp[u] = __float2bfloat16(Ls[jr][t * 8 + u]);
  *(uint4v*)(xT + (size_t)(bb * PIX + p0 + jr) * CDIM + c0 + t * 8) = *(uint4v*)tmp;
}

// ---------------- MFMA GEMM: Y[o][gp] = sum_c W[o][c] * Bm[gp][c] -----------
#define MG_QKV 0
#define MG_PROJ 1
#define MG_GELU 2
#define MG_C2 3
#define MGS 2056

template <int EPI>
__global__ __launch_bounds__(256) void mgemm_k(
    const u16* __restrict__ Bm, const u16* __restrict__ Apk,
    const float* __restrict__ bias,
    float* __restrict__ outF, u16* __restrict__ outT, u16* __restrict__ outT2,
    const float* __restrict__ extra, int Cin) {
  __shared__ __align__(16) u16 Bs[8 * MGS];  // 32.9 KB
  int tid = threadIdx.x;
  int lane = tid & 63, wid = tid >> 6;
  int hi = lane >> 5, ln31 = lane & 31;
  int p0 = blockIdx.x * 256;
  int o0 = blockIdx.y * 64;
  int nK = Cin >> 4;
  f32x16 acc[2][2];
#pragma unroll
  for (int mt = 0; mt < 2; mt++)
#pragma unroll
    for (int nt = 0; nt < 2; nt++)
#pragma unroll
      for (int i = 0; i < 16; i++) acc[mt][nt][i] = 0.f;

  for (int cc = 0; cc < Cin; cc += 64) {
#pragma unroll
    for (int i = 0; i < 8; i++) {
      int idx = i * 256 + tid;
      int g = idx & 7, p = idx >> 3;
      uint4v v = *(const uint4v*)(Bm + (size_t)(p0 + p) * Cin + cc + g * 8);
      *(uint4v*)&Bs[g * MGS + p * 8] = v;
    }
    __syncthreads();
    const u16* Ab = Apk + ((size_t)(o0 >> 5) * nK + (cc >> 4)) * 512 + lane * 8;
    int pA = wid * 64 + ln31;
    int pB = pA + 32;
#pragma unroll
    for (int ks = 0; ks < 4; ks++) {
      int g = ks * 2 + hi;
      bf16x8 b0 = *(const bf16x8*)&Bs[g * MGS + pA * 8];
      bf16x8 b1 = *(const bf16x8*)&Bs[g * MGS + pB * 8];
      bf16x8 a0 = *(const bf16x8*)(Ab + ks * 512);
      bf16x8 a1 = *(const bf16x8*)(Ab + (nK + ks) * 512);
      acc[0][0] = __builtin_amdgcn_mfma_f32_32x32x16_bf16(a0, b0, acc[0][0], 0, 0, 0);
      acc[0][1] = __builtin_amdgcn_mfma_f32_32x32x16_bf16(a0, b1, acc[0][1], 0, 0, 0);
      acc[1][0] = __builtin_amdgcn_mfma_f32_32x32x16_bf16(a1, b0, acc[1][0], 0, 0, 0);
      acc[1][1] = __builtin_amdgcn_mfma_f32_32x32x16_bf16(a1, b1, acc[1][1], 0, 0, 0);
    }
    __syncthreads();
  }

  // ---- epilogue ----
  if (EPI == MG_C2) {
#pragma unroll
    for (int mt = 0; mt < 2; mt++)
#pragma unroll
      for (int r = 0; r < 16; r++) {
        int o = o0 + mt * 32 + (r & 3) + 8 * (r >> 2) + 4 * hi;
        float bv = bias[o];
#pragma unroll
        for (int nt = 0; nt < 2; nt++) {
          unsigned gp = p0 + wid * 64 + nt * 32 + ln31;
          unsigned bb = gp / PIX, pp = gp - bb * PIX;
          size_t oi = ((size_t)bb * CDIM + o) * PIX + pp;
          outF[oi] = acc[mt][nt][r] + bv + extra[oi];
        }
      }
  } else {
    // bf16-transposed output via wave-local LDS transpose (Bs reused as scratch)
#pragma unroll
    for (int mt = 0; mt < 2; mt++)
#pragma unroll
      for (int r = 0; r < 16; r++) {
        int o_loc = mt * 32 + (r & 3) + 8 * (r >> 2) + 4 * hi;
        int o = o0 + o_loc;
        float bv = bias[o];
#pragma unroll
        for (int nt = 0; nt < 2; nt++) {
          int p_loc = wid * 64 + nt * 32 + ln31;
          float val = acc[mt][nt][r] + bv;
          if (EPI == MG_PROJ) {
            unsigned gp = p0 + p_loc;
            unsigned bb = gp / PIX, pp = gp - bb * PIX;
            size_t oi = ((size_t)bb * CDIM + o) * PIX + pp;
            val += extra[oi];
            outF[oi] = val;
          }
          if (EPI == MG_GELU)
            val = 0.5f * val * (1.f + erff(val * 0.70710678118654752f));
          *(__hip_bfloat16*)&Bs[p_loc * 64 + (((o_loc >> 3) ^ (p_loc & 7)) << 3) + (o_loc & 7)] =
              __float2bfloat16(val);
        }
      }
    int prow = wid * 64 + lane;
    int psw = prow & 7;
    uint4v r8[8];
#pragma unroll
    for (int g = 0; g < 8; g++)
      r8[g] = *(const uint4v*)&Bs[prow * 64 + ((g ^ psw) << 3)];
    unsigned gp = p0 + prow;
    if (EPI == MG_QKV) {
      unsigned bb = gp / PIX, pp = gp - bb * PIX;
      int s = o0 / 192;               // 0=q, 1=k, 2=v
      int rr = o0 - s * 192;
      int h0 = rr >> 5;
      if (s < 2) {
        u16* d0 = outT + ((size_t)(bb * NHEADS + h0) * PIX + pp) * 64 + s * 32;
        u16* d1 = outT + ((size_t)(bb * NHEADS + h0 + 1) * PIX + pp) * 64 + s * 32;
        *(uint4v*)(d0) = r8[0]; *(uint4v*)(d0 + 8) = r8[1];
        *(uint4v*)(d0 + 16) = r8[2]; *(uint4v*)(d0 + 24) = r8[3];
        *(uint4v*)(d1) = r8[4]; *(uint4v*)(d1 + 8) = r8[5];
        *(uint4v*)(d1 + 16) = r8[6]; *(uint4v*)(d1 + 24) = r8[7];
      } else {                        // v -> vT[img][pix][32] bf16
        u16* d0 = outT2 + ((size_t)(bb * NHEADS + h0) * PIX + pp) * 32;
        u16* d1 = outT2 + ((size_t)(bb * NHEADS + h0 + 1) * PIX + pp) * 32;
        *(uint4v*)(d0) = r8[0]; *(uint4v*)(d0 + 8) = r8[1];
        *(uint4v*)(d0 + 16) = r8[2]; *(uint4v*)(d0 + 24) = r8[3];
        *(uint4v*)(d1) = r8[4]; *(uint4v*)(d1 + 8) = r8[5];
        *(uint4v*)(d1 + 16) = r8[6]; *(uint4v*)(d1 + 24) = r8[7];
      }
    } else if (EPI == MG_PROJ) {
      u16* d = outT + (size_t)gp * CDIM + o0;
#pragma unroll
      for (int g = 0; g < 8; g++) *(uint4v*)(d + g * 8) = r8[g];
    } else {  // GELU -> hT [gp][768]
      u16* d = outT + (size_t)gp * 768 + o0;
#pragma unroll
      for (int g = 0; g < 8; g++) *(uint4v*)(d + g * 8) = r8[g];
    }
  }
}

// ------ 7x7 attn conv (round-3 core) + FUSED softmax + PV -> attnoT bf16 ----
// Block = (img, 8x8 tile). 4 waves = Mtile x Ntile. After the MFMA loop the
// block holds all 64ko x 64px logits -> LDS softmax over 49 -> VALU PV with
// bf16 v-patch -> attnoT. attnL never materialized.
#define VPS 40  // vp per-pixel stride (u16): 32 payload + 8 pad (bank spread)
__global__ __launch_bounds__(256) void attn_fused_k(
    const u16* __restrict__ qkT, const u16* __restrict__ wTb2,
    const u16* __restrict__ vT,
    const float* __restrict__ dm_b, const float* __restrict__ rel_bias,
    u16* __restrict__ attnoT) {
  // raw LDS: phase1 patch = 12544 u16 (25088B); phase2 smx 16384B + vp 15680B
  __shared__ __align__(16) u16 shraw[16032];
  u16* patch = shraw;
  int img = blockIdx.x / 49;
  int tile = blockIdx.x % 49;
  int y0 = (tile / 7) * 8, x0 = (tile % 7) * 8;
  int tid = threadIdx.x;
  const u16* qbase = qkT + (size_t)img * PIX * 64;
  for (int idx = tid; idx < 1568; idx += 256) {
    int pix = idx >> 3, g = idx & 7;
    int r = pix / 14, c = pix - r * 14;
    int gy = y0 - 3 + r, gx = x0 - 3 + c;
    uint4v val = {0u, 0u, 0u, 0u};
    if ((unsigned)gy < 56u && (unsigned)gx < 56u)
      val = *(const uint4v*)(qbase + (size_t)(gy * 56 + gx) * 64 + g * 8);
    *(uint4v*)&patch[pix * 64 + ((g ^ (pix & 7)) << 3)] = val;
  }
  __syncthreads();

  int lane = tid & 63, wid = tid >> 6;
  int Mtile = wid & 1, Ntile = wid >> 1;
  int n = lane & 31, kgrp = lane >> 5;
  int py = Ntile * 4 + (n >> 3), px = n & 7;
  f32x16 acc;
#pragma unroll
  for (int i = 0; i < 16; i++) acc[i] = 0.f;

  const u16* Abase = wTb2 + (size_t)Mtile * 49 * 4 * 512 + lane * 8;
#pragma unroll
  for (int kh = 0; kh < 7; kh++) {
#pragma unroll
    for (int kw = 0; kw < 7; kw++) {
      int tap = kh * 7 + kw;
      int lp = (py + kh) * 14 + px + kw;
      int lpand = lp & 7;
#pragma unroll
      for (int ch = 0; ch < 4; ch++) {
        bf16x8 a = __builtin_bit_cast(bf16x8,
            *(const uint4v*)(Abase + (size_t)(tap * 4 + ch) * 512));
        int g = ch * 2 + kgrp;
        bf16x8 bb = __builtin_bit_cast(bf16x8,
            *(const uint4v*)&patch[lp * 64 + ((g ^ lpand) << 3)]);
        acc = __builtin_amdgcn_mfma_f32_32x32x16_bf16(a, bb, acc, 0, 0, 0);
      }
    }
  }

  // ---- fused tail: logits -> LDS, v-patch -> LDS, softmax, PV --------------
  __syncthreads();                       // patch reads done; safe to overwrite
  float* smx = (float*)shraw;            // [64 ko][64 px] fp32
  u16* vp = shraw + 8192;                // [196 pix][VPS] bf16
  int head = img % NHEADS;
#pragma unroll
  for (int r = 0; r < 16; r++) {
    int ko = Mtile * 32 + (r & 3) + 8 * (r >> 2) + 4 * kgrp;
    if (ko < KWIN)
      smx[ko * 64 + Ntile * 32 + n] = acc[r] + dm_b[ko] + rel_bias[ko * NHEADS + head];
  }
  const u16* vbase = vT + (size_t)img * PIX * 32;
  for (int idx = tid; idx < 784; idx += 256) {
    int g = idx & 3, lp = idx >> 2;
    int r = lp / 14, c = lp - r * 14;
    int gy = y0 - 3 + r, gx = x0 - 3 + c;
    uint4v val = {0u, 0u, 0u, 0u};
    if ((unsigned)gy < 56u && (unsigned)gx < 56u)
      val = *(const uint4v*)(vbase + (size_t)(gy * 56 + gx) * 32 + g * 8);
    *(uint4v*)&vp[lp * VPS + g * 8] = val;
  }
  __syncthreads();
  if (tid < 64) {                        // softmax columns (2 lanes/bank: free)
    float a[KWIN];
    float m = -1e30f;
#pragma unroll
    for (int k = 0; k < KWIN; k++) { a[k] = smx[k * 64 + tid]; m = fmaxf(m, a[k]); }
    float s = 0.f;
#pragma unroll
    for (int k = 0; k < KWIN; k++) { a[k] = __expf(a[k] - m); s += a[k]; }
    float inv = 1.f / s;
#pragma unroll
    for (int k = 0; k < KWIN; k++) smx[k * 64 + tid] = a[k] * inv;
  }
  __syncthreads();
  int pxl = tid & 63, co = tid >> 6;
  int pyy = pxl >> 3, pxx = pxl & 7;
  float o8[8] = {0.f, 0.f, 0.f, 0.f, 0.f, 0.f, 0.f, 0.f};
#pragma unroll
  for (int kh = 0; kh < 7; kh++) {
#pragma unroll
    for (int kw = 0; kw < 7; kw++) {
      float p = smx[(kh * 7 + kw) * 64 + pxl];
      bf16x8 v = *(const bf16x8*)&vp[((pyy + kh) * 14 + pxx + kw) * VPS + co * 8];
#pragma unroll
      for (int j = 0; j < 8; j++) o8[j] += p * (float)v[j];
    }
  }
  int gp = (y0 + pyy) * 56 + x0 + pxx;
  int b = img / NHEADS;
  __hip_bfloat16 ob[8];
#pragma unroll
  for (int j = 0; j < 8; j++) ob[j] = __float2bfloat16(o8[j]);
  *(uint4v*)(attnoT + ((size_t)b * PIX + gp) * CDIM + head * 32 + co * 8) = *(uint4v*)ob;
}

// ---------------- launch ----------------------------------------------------
extern "C" void kernel_launch(void* const* d_in, const int* in_sizes, int n_in,
                              void* d_out, int out_size, void* d_ws, size_t ws_size,
                              hipStream_t stream) {
  const float* x        = (const float*)d_in[0];
  const float* bn_gamma = (const float*)d_in[1];
  const float* bn_beta  = (const float*)d_in[2];
  const float* qkv_w    = (const float*)d_in[3];
  const float* qkv_b    = (const float*)d_in[4];
  const float* dm_w     = (const float*)d_in[5];
  const float* dm_b     = (const float*)d_in[6];
  const float* rel_bias = (const float*)d_in[7];
  const float* proj_w   = (const float*)d_in[8];
  const float* proj_b   = (const float*)d_in[9];
  const float* c1_w     = (const float*)d_in[10];
  const float* c1_b     = (const float*)d_in[11];
  const float* c2_w     = (const float*)d_in[12];
  const float* c2_b     = (const float*)d_in[13];
  float* out = (float*)d_out;
  float* ws  = (float*)d_ws;

  float* stats   = ws;                          // 384 f
  float* b_eff   = stats + 384;                 // 576 f
  u16*   pk_qkv  = (u16*)(b_eff + 576);         // 110592 u16
  u16*   pk_proj = pk_qkv + 110592;             // 36864
  u16*   pk_c1   = pk_proj + 36864;             // 147456
  u16*   pk_c2   = pk_c1 + 147456;              // 147456
  u16*   wTb2    = pk_c2 + 147456;              // 200704
  u16*   xT      = wTb2 + 200704;               // 2408448 u16
  u16*   qkT     = xT + 2408448;                // 4816896 u16
  u16*   vT      = qkT + 4816896;               // 2408448 u16
  u16*   attnoT  = vT + 2408448;                // 2408448 u16
  float* x1      = (float*)(attnoT + 2408448);  // 2408448 f
  u16*   x1T     = (u16*)(x1 + 2408448);        // 2408448 u16
  u16*   hT      = xT;  // alias: 9633792 u16 over dead xT+qkT+vT

  bn_stats_k<<<CDIM, 256, 0, stream>>>(x, stats);
  fold_pack_k<<<576, 192, 0, stream>>>(qkv_w, qkv_b, bn_gamma, bn_beta, stats,
                                       pk_qkv, b_eff);
  prep2_k<<<946, 256, 0, stream>>>(dm_w, wTb2, proj_w, pk_proj, c1_w, pk_c1,
                                   c2_w, pk_c2);
  xT_k<<<dim3(BATCH * 49, 6), 256, 0, stream>>>(x, xT);

  mgemm_k<MG_QKV><<<dim3(49, 9), 256, 0, stream>>>(
      xT, pk_qkv, b_eff, nullptr, qkT, vT, nullptr, 192);
  attn_fused_k<<<NIMG * 49, 256, 0, stream>>>(qkT, wTb2, vT, dm_b, rel_bias, attnoT);
  mgemm_k<MG_PROJ><<<dim3(49, 3), 256, 0, stream>>>(
      attnoT, pk_proj, proj_b, x1, x1T, nullptr, x, 192);
  mgemm_k<MG_GELU><<<dim3(49, 12), 256, 0, stream>>>(
      x1T, pk_c1, c1_b, nullptr, hT, nullptr, nullptr, 192);
  mgemm_k<MG_C2><<<dim3(49, 3), 256, 0, stream>>>(
      hT, pk_c2, c2_b, out, nullptr, nullptr, x1, 768);
}